// Round 1
// baseline (149.095 us; speedup 1.0000x reference)
//
#include <hip/hip_runtime.h>
#include <hip/hip_bf16.h>

#define DDIM 256
#define NROWS 8192

typedef __attribute__((ext_vector_type(8))) __bf16 bf16x8;
typedef __attribute__((ext_vector_type(4))) float floatx4;

// async global->LDS, 16B per lane. LDS dest is wave-uniform base + lane*16.
__device__ __forceinline__ void async16(const void* g, void* l) {
    __builtin_amdgcn_global_load_lds(
        (const __attribute__((address_space(1))) unsigned int*)g,
        (__attribute__((address_space(3))) unsigned int*)l,
        16, 0, 0);
}

// raw v_exp_f32: returns 2^x (one transcendental, no extra mul like __expf)
__device__ __forceinline__ float fexp2(float x) {
    float r; asm("v_exp_f32 %0, %1" : "=v"(r) : "v"(x)); return r;
}

// Stage rows_per_wave rows (full K=256, 512 B/row) per wave into LDS at l,
// linear layout with granule swizzle: stored granule position g holds logical
// granule g ^ (row&7). One async16 covers 2 rows (64 lanes x 16 B).
// (Used for the one-time A-stripe staging.)
__device__ __forceinline__ void stage_rows(const unsigned short* __restrict__ g,
                                           unsigned short* l,
                                           int wv, int lane,
                                           int rows_per_wave, int ninstr)
{
    const int lrow = lane >> 5;       // 0..1
    const int gcol = lane & 31;       // granule 0..31
    const int r0 = wv * rows_per_wave;
    for (int j = 0; j < ninstr; ++j) {
        const int rb = r0 + j * 2;
        const int r  = rb + lrow;
        const int gg = gcol ^ (r & 7);
        async16(g + (size_t)r * DDIM + gg * 8, l + (size_t)rb * DDIM);
    }
}

__device__ __forceinline__ bf16x8 frag(const unsigned short* base, int row,
                                       int ks, int q, int m)
{
    return *(const bf16x8*)&base[(size_t)row * DDIM
                                 + (((ks * 4 + q) ^ (m & 7)) * 8)];
}

// Kernel 1: L2-normalize rows of U and P to bf16, compute pos_sim, zero
// rowsum / out / ticket counter. One wave per row.
__global__ __launch_bounds__(256) void normalize_kernel(
    const float* __restrict__ U, const float* __restrict__ P,
    unsigned short* __restrict__ Un, unsigned short* __restrict__ Pn,
    float* __restrict__ possim, float* __restrict__ rowsum,
    float* __restrict__ out, int* __restrict__ counter)
{
    if (blockIdx.x == 0 && threadIdx.x == 0) { out[0] = 0.0f; counter[0] = 0; }
    const int lane = threadIdx.x & 63;
    const int row  = blockIdx.x * 4 + (threadIdx.x >> 6);
    const size_t base = (size_t)row * DDIM + lane * 4;
    const float4 u4 = *(const float4*)(U + base);
    const float4 p4 = *(const float4*)(P + base);
    float su = u4.x*u4.x + u4.y*u4.y + u4.z*u4.z + u4.w*u4.w;
    float sp = p4.x*p4.x + p4.y*p4.y + p4.z*p4.z + p4.w*p4.w;
    float up = u4.x*p4.x + u4.y*p4.y + u4.z*p4.z + u4.w*p4.w;
    #pragma unroll
    for (int d = 1; d < 64; d <<= 1) {
        su += __shfl_xor(su, d);
        sp += __shfl_xor(sp, d);
        up += __shfl_xor(up, d);
    }
    const float iu = rsqrtf(fmaxf(su, 1e-24f));
    const float ip = rsqrtf(fmaxf(sp, 1e-24f));
    if (lane == 0) {
        possim[row] = up * iu * ip;
        rowsum[row] = 0.0f;
    }
    union { ushort4 s4; __hip_bfloat16 h[4]; } cu, cp;
    cu.h[0] = __float2bfloat16(u4.x * iu); cu.h[1] = __float2bfloat16(u4.y * iu);
    cu.h[2] = __float2bfloat16(u4.z * iu); cu.h[3] = __float2bfloat16(u4.w * iu);
    cp.h[0] = __float2bfloat16(p4.x * ip); cp.h[1] = __float2bfloat16(p4.y * ip);
    cp.h[2] = __float2bfloat16(p4.z * ip); cp.h[3] = __float2bfloat16(p4.w * ip);
    *(ushort4*)(Un + base) = cu.s4;
    *(ushort4*)(Pn + base) = cp.s4;
}

// Stage one 32-row (16 KB) B tile into LDS buffer `buf`; 4 async16 per wave.
// boff[jj] = per-lane swizzled byte offset within a tile (iter-invariant).
__device__ __forceinline__ void stage_tile(const unsigned short* __restrict__ Bglob,
                                           const unsigned* boff,
                                           unsigned short* lds,
                                           int t, int buf, int wv)
{
    const char* src = (const char*)Bglob + (unsigned)t * 16384u;
    char* dst = (char*)lds + buf * 16384 + wv * 4096;
    #pragma unroll
    for (int jj = 0; jj < 4; ++jj)
        async16(src + boff[jj], dst + jj * 1024);
}

// Compute one 32-col tile from LDS buffer J (compile-time -> immediate DS
// offsets). bb[h][ks&1] are per-lane base byte offsets (swizzle pre-folded):
//   addr = bb[h][ks&1] + J*16384 + (ks>>1)*128   (max 65520 < 64 KiB)
// which reproduces frag(): row*512 + (((ks*4+q)^(m&7))*16.
template<int J>
__device__ __forceinline__ void compute_tile(const unsigned short* lds,
        const unsigned (&bb)[2][2], const bf16x8 (&afr)[2][8],
        float (&rowpart)[2][4])
{
    floatx4 acc[2][2];
    #pragma unroll
    for (int t = 0; t < 2; ++t) {
        acc[t][0] = {0.0f, 0.0f, 0.0f, 0.0f};
        acc[t][1] = {0.0f, 0.0f, 0.0f, 0.0f};
    }
    const char* base = (const char*)lds;
    #pragma unroll
    for (int ks = 0; ks < 8; ++ks) {
        const bf16x8 b0 = *(const bf16x8*)(base + bb[0][ks & 1]
                                           + (J * 16384 + (ks >> 1) * 128));
        const bf16x8 b1 = *(const bf16x8*)(base + bb[1][ks & 1]
                                           + (J * 16384 + (ks >> 1) * 128));
        #pragma unroll
        for (int t = 0; t < 2; ++t) {
            acc[t][0] = __builtin_amdgcn_mfma_f32_16x16x32_bf16(
                afr[t][ks], b0, acc[t][0], 0, 0, 0);
            acc[t][1] = __builtin_amdgcn_mfma_f32_16x16x32_bf16(
                afr[t][ks], b1, acc[t][1], 0, 0, 0);
        }
    }
    // exp(5*sim) = 2^(sim * 5*log2(e)); C/D: col = m, row = q*4 + r (+t*16)
    #pragma unroll
    for (int t = 0; t < 2; ++t)
        #pragma unroll
        for (int h = 0; h < 2; ++h)
            #pragma unroll
            for (int r = 0; r < 4; ++r)
                rowpart[t][r] += fexp2(acc[t][h][r] * 7.2134752044448169f);
}

// Kernel 2: persistent-A GEMM + exp-rowsum + fused finalize.
// 512 blocks (2/CU, 64.5 KB LDS), 4 waves, wave = 32 rows x full tile width.
// afr[2][8] = 64 regs (+acc 16) keeps unified VGPR+AGPR < 256/wave so
// 2 waves/SIMD are truly resident (the old 2x2 wave grid needed ~276 -> 1).
// B quad-buffered 4 x 16 KB, prefetch depth 3, counted s_waitcnt vmcnt(8)
// per slot -- the main loop never drains vmcnt to 0.
__global__ __launch_bounds__(256, 2) void sim_exp_rowsum(
    const unsigned short* __restrict__ Un,
    const unsigned short* __restrict__ Pn,
    float* __restrict__ rowsum,
    const float* __restrict__ possim,
    int* __restrict__ counter,
    float* __restrict__ out)
{
    __shared__ __align__(16) unsigned short lds[32768];   // 64 KB: 4 x 16 KB B bufs; A transient
    __shared__ float ws4[4];
    __shared__ int ticket_s;

    const int tid  = threadIdx.x;
    const int lane = tid & 63;
    const int wv   = tid >> 6;          // 0..3, each wave owns 32 A-rows
    const int m = lane & 15;
    const int q = lane >> 4;

    const int stripe = blockIdx.x >> 3;   // 0..63
    const int oct    = blockIdx.x & 7;    // 0..7 (== XCD under %8 round-robin)

    // ---- Prologue: stage A stripe (128 rows), pull A-frags to registers ----
    const unsigned short* Aglob = Un + (size_t)stripe * 128 * DDIM;
    stage_rows(Aglob, lds, wv, lane, 32, 16);
    __syncthreads();

    bf16x8 afr[2][8];
    #pragma unroll
    for (int t = 0; t < 2; ++t)
        #pragma unroll
        for (int ks = 0; ks < 8; ++ks)
            afr[t][ks] = frag(lds, wv * 32 + t * 16 + m, ks, q, m);
    __syncthreads();   // drains lgkm: all waves have A in regs; LDS free for B

    // ---- Hoisted per-lane addressing ----
    // ds-read bases: (h*16+m)*512 + ((q^c10)<<4) + ((par^c2)<<6),
    // c = m&7 split as c10 (low2) / c2 (bit2); par = ks&1.
    const int c10 = m & 3, c2 = (m >> 2) & 1;
    unsigned bb[2][2];
    #pragma unroll
    for (int h = 0; h < 2; ++h)
        #pragma unroll
        for (int par = 0; par < 2; ++par)
            bb[h][par] = (unsigned)((h * 16 + m) * 512
                                    + ((q ^ c10) << 4) + ((par ^ c2) << 6));

    // stage offsets: per wave 8 rows/tile (4 async16); r&7 is tile-invariant
    // (tiles are 32 rows, wv*8 is 0 mod 8) so the granule swizzle hoists.
    const int lrow = lane >> 5, gcol = lane & 31;
    unsigned boff[4];
    #pragma unroll
    for (int jj = 0; jj < 4; ++jj) {
        const int r = wv * 8 + jj * 2 + lrow;
        const int gg = gcol ^ (r & 7);
        boff[jj] = (unsigned)(r * 512 + gg * 16);
    }

    const unsigned short* Bglob = Pn + (size_t)(oct * 1024) * DDIM;
    float rowpart[2][4] = {{0.f, 0.f, 0.f, 0.f}, {0.f, 0.f, 0.f, 0.f}};

    // ---- Main loop: 32 col-tiles of 32, quad-buffered, depth-3 prefetch ----
    stage_tile(Bglob, boff, lds, 0, 0, wv);
    stage_tile(Bglob, boff, lds, 1, 1, wv);
    stage_tile(Bglob, boff, lds, 2, 2, wv);   // 12 loads in flight

    // Slot for tile T (buf J=T&3): wait own ds_reads done (free), wait the
    // oldest in-flight tile's 4 loads retired (counted, never 0 mid-loop),
    // barrier, issue tile T+3 into buf (T+3)&3 (its old contents were
    // consumed at tile T-1, before this barrier), compute tile T.
#define SLOT(JBUF, NWAIT, DOSTAGE, STAGET)                                   \
    do {                                                                     \
        asm volatile("s_waitcnt lgkmcnt(0)" ::: "memory");                   \
        asm volatile("s_waitcnt vmcnt(" #NWAIT ")" ::: "memory");            \
        __builtin_amdgcn_s_barrier();                                        \
        if (DOSTAGE)                                                         \
            stage_tile(Bglob, boff, lds, (STAGET), (STAGET) & 3, wv);        \
        compute_tile<JBUF>(lds, bb, afr, rowpart);                           \
    } while (0)

    for (int i = 0; i < 7; ++i) {         // tiles 0..27
        const int t0 = i * 4;
        SLOT(0, 8, true, t0 + 3);
        SLOT(1, 8, true, t0 + 4);
        SLOT(2, 8, true, t0 + 5);
        SLOT(3, 8, true, t0 + 6);
    }
    SLOT(0, 8, true, 31);                 // tile 28
    SLOT(1, 8, false, 0);                 // tile 29
    SLOT(2, 4, false, 0);                 // tile 30
    SLOT(3, 0, false, 0);                 // tile 31
#undef SLOT

    // ---- Epilogue: reduce 16 column-lanes, one atomic per row per wave ----
    #pragma unroll
    for (int t = 0; t < 2; ++t) {
        #pragma unroll
        for (int r = 0; r < 4; ++r) {
            float s = rowpart[t][r];
            s += __shfl_xor(s, 1);
            s += __shfl_xor(s, 2);
            s += __shfl_xor(s, 4);
            s += __shfl_xor(s, 8);
            if (m == 0) {
                const int grow = stripe * 128 + wv * 32 + t * 16 + q * 4 + r;
                atomicAdd(&rowsum[grow], s);
            }
        }
    }

    // ---- Fused finalize: last block computes the loss ----
    __threadfence();
    __syncthreads();   // this block's atomics are visible
    if (tid == 0)
        ticket_s = __hip_atomic_fetch_add(counter, 1, __ATOMIC_ACQ_REL,
                                          __HIP_MEMORY_SCOPE_AGENT);
    __syncthreads();
    if (ticket_s == 511) {
        float part = 0.0f;
        for (int i = tid; i < NROWS; i += 256) {
            const float rs = __hip_atomic_load(&rowsum[i], __ATOMIC_RELAXED,
                                               __HIP_MEMORY_SCOPE_AGENT);
            part += __logf(rs) - 5.0f * possim[i];
        }
        #pragma unroll
        for (int d = 1; d < 64; d <<= 1) part += __shfl_xor(part, d);
        if (lane == 0) ws4[wv] = part;
        __syncthreads();
        if (tid == 0)
            out[0] = (ws4[0] + ws4[1] + ws4[2] + ws4[3]) * (1.0f / (float)NROWS);
    }
}

extern "C" void kernel_launch(void* const* d_in, const int* in_sizes, int n_in,
                              void* d_out, int out_size, void* d_ws, size_t ws_size,
                              hipStream_t stream) {
    const float* U = (const float*)d_in[0];
    const float* P = (const float*)d_in[1];
    float* out = (float*)d_out;
    char* ws = (char*)d_ws;
    // ws: Un bf16 (4 MB) | Pn bf16 (4 MB) | rowsum f32 (32 KB) | possim f32 (32 KB) | counter
    unsigned short* Un = (unsigned short*)ws;
    unsigned short* Pn = (unsigned short*)(ws + 4194304);
    float* rowsum = (float*)(ws + 8388608);
    float* possim = (float*)(ws + 8388608 + 32768);
    int* counter  = (int*)(ws + 8388608 + 65536);

    normalize_kernel<<<NROWS / 4, 256, 0, stream>>>(U, P, Un, Pn, possim, rowsum,
                                                    out, counter);
    sim_exp_rowsum<<<512, 256, 0, stream>>>(Un, Pn, rowsum, possim, counter, out);
}